// Round 9
// baseline (161.581 us; speedup 1.0000x reference)
//
#include <hip/hip_runtime.h>
#include <hip/hip_bf16.h>

// CausalAttentionPixelBlock: 24 independent causal attns (3 stacks x 8 heads),
// seq=2048, head dim ck=8, fp32 in/out, channels-first [c][pos].
// ROUND 8 = MEASUREMENT ROUND: kernels byte-identical to round 7; attn_main is
// launched 5x (pure/idempotent) so dur_us decomposes prepass vs attn_main:
// dur7 = floor + P + A (=92, P+A=33);  dur8 = floor + P + 5A + 4*node_ovh.
constexpr int NPROB  = 24;
constexpr int SEQ    = 2048;
constexpr int CK     = 8;
constexpr int NSTRIP = SEQ / 16;   // 128 strips of 16 query rows per prob

typedef __attribute__((ext_vector_type(8))) short bf16x8;  // MFMA A/B frag (8 bf16)
typedef __attribute__((ext_vector_type(4))) float f32x4;   // MFMA C/D frag

// ck^-0.5 * log2(e): exp(x) -> exp2(x') with scale folded into Q
__device__ constexpr float QSCALE = 0.35355339059327373f * 1.4426950408889634f;

__device__ inline unsigned packbf(float a, float b) {
    float2 t{a, b};
    __hip_bfloat162 h = __float22bfloat162_rn(t);
    unsigned r; __builtin_memcpy(&r, &h, 4); return r;
}

// ---------------- prepass: fp32 -> bf16 fragments in ws ----------------
// Qt: [prob][j][8] bf16 (Q transposed, pre-scaled)                     786 KB
// Kt: [prob][j][8] bf16 (K transposed)                                 786 KB
// V16:[prob][chunk][64] uint4, chunk = 32 keys. Entry (chunk p, l=g*16+row):
//     V[row][32p + {4g..4g+3, 16+4g..16+4g+3}] (sigma key order). Row 8 = 1.0
//     (free rowsum), rows 9-15 = 0. PV B-frag lane l reads entry l ->
//     wave vf load = 64 consecutive uint4 (coalesced).                 1.57 MB
constexpr int T1 = NPROB * SEQ;            // Qt+Kt items (one j each)
constexpr int T2 = NPROB * CK * (SEQ / 8); // V16 rows 0-7 (one uint4 each)
constexpr int T3 = NPROB * 8  * (SEQ / 8); // V16 rows 8-15 fill

__global__ __launch_bounds__(256) void prepass(
    const float* __restrict__ K, const float* __restrict__ Q,
    const float* __restrict__ V,
    uint4* __restrict__ Qt4, uint4* __restrict__ Kt4, uint4* __restrict__ V164)
{
    const int t = blockIdx.x * 256 + threadIdx.x;
    if (t < T1) {
        const int prob = t >> 11, j = t & (SEQ - 1);
        const float* qs = Q + prob * CK * SEQ + j;
        const float* ks = K + prob * CK * SEQ + j;
        uint4 qo, ko;
        qo.x = packbf(qs[0 * SEQ] * QSCALE, qs[1 * SEQ] * QSCALE);
        qo.y = packbf(qs[2 * SEQ] * QSCALE, qs[3 * SEQ] * QSCALE);
        qo.z = packbf(qs[4 * SEQ] * QSCALE, qs[5 * SEQ] * QSCALE);
        qo.w = packbf(qs[6 * SEQ] * QSCALE, qs[7 * SEQ] * QSCALE);
        ko.x = packbf(ks[0 * SEQ], ks[1 * SEQ]);
        ko.y = packbf(ks[2 * SEQ], ks[3 * SEQ]);
        ko.z = packbf(ks[4 * SEQ], ks[5 * SEQ]);
        ko.w = packbf(ks[6 * SEQ], ks[7 * SEQ]);
        Qt4[t] = qo;  // index = prob*SEQ + j
        Kt4[t] = ko;
    } else if (t < T1 + T2) {
        const int idx  = t - T1;
        const int prob = idx >> 11;
        const int rem  = idx & 2047;
        const int c    = rem >> 8;             // V row (channel) 0..7
        const int u    = rem & 255;
        const int c32  = u >> 2;               // 32-key chunk 0..63
        const int g    = u & 3;                // k-group within chunk
        const float* vs = V + prob * CK * SEQ + c * SEQ + c32 * 32;
        const float4 a = *reinterpret_cast<const float4*>(vs + 4 * g);       // keys 4g..4g+3
        const float4 b = *reinterpret_cast<const float4*>(vs + 16 + 4 * g);  // keys 16+4g..
        uint4 vo;
        vo.x = packbf(a.x, a.y); vo.y = packbf(a.z, a.w);
        vo.z = packbf(b.x, b.y); vo.w = packbf(b.z, b.w);
        V164[prob * 4096 + c32 * 64 + g * 16 + c] = vo;   // [prob][chunk][g*16+row]
    } else {
        const int idx  = t - T1 - T2;
        const int prob = idx >> 11;
        const int rem  = idx & 2047;
        const int r    = rem >> 8;             // 0..7 -> row 8+r
        const int u    = rem & 255;
        const int c32  = u >> 2;
        const int g    = u & 3;
        const unsigned w = (r == 0) ? 0x3F803F80u : 0u;  // row 8 = ones (rowsum)
        V164[prob * 4096 + c32 * 64 + g * 16 + (8 + r)] = uint4{w, w, w, w};
    }
}

// ---------------- main: one 4-wave block per 16-row strip ----------------
// QK transposed: d = mfma16x16x32(A=K, B=Q) -> lane(g,li) reg r = P[j'=4g+r(+16)][i'=li].
// exp2 in place, pack to bf16: pa = {d0r01, d0r23, d1r01, d1r23} is EXACTLY the
// PV A-frag under key-order sigma(8g+e) = 4g+e | 16+4g+(e-4); V staged in sigma
// order, so PV = mfma(A=pa, B=V) with no cross-lane ops. V row 8 = ones gives
// the softmax denominator in acc col 8.
__global__ __launch_bounds__(256) void attn_main(
    const uint4* __restrict__ Qt4, const uint4* __restrict__ Kt4,
    const uint4* __restrict__ V164, float* __restrict__ OUT)
{
    const int bid   = blockIdx.x;
    const int prob  = bid % NPROB;
    const int strip = (NSTRIP - 1) - (bid / NPROB);  // longest first
    const int i0    = strip * 16;
    const int t  = threadIdx.x;
    const int w  = t >> 6;                  // wave 0..3
    const int l  = t & 63;                  // lane
    const int li = l & 15, g = l >> 4;

    const uint4* Ktp = Kt4 + prob * SEQ;
    const uint4* Vp  = V164 + prob * 4096;  // [64 chunks][64] uint4

    union { bf16x8 v; uint4 u; } qf;
    qf.u = (g == 0) ? Qt4[prob * SEQ + i0 + li] : uint4{0, 0, 0, 0};

    f32x4 acc = {0.f, 0.f, 0.f, 0.f};
    const f32x4 zc = {0.f, 0.f, 0.f, 0.f};
    const int mconst = li - 4 * g;          // diag tile: keep reg r iff r <= mconst

    const int NU = i0 >> 5;                 // fully-unmasked 32-j iterations

#pragma unroll 2
    for (int p = w; p < NU; p += 4) {
        const int j0 = p * 32;
        union { bf16x8 v; uint4 u; } k0, k1, vf;
        k0.u = Ktp[j0 + li];                // keys j0..j0+15 (broadcast x4)
        k1.u = Ktp[j0 + 16 + li];           // keys j0+16..j0+31
        vf.u = Vp[(p << 6) + l];            // sigma-interleaved V, coalesced
        f32x4 d0 = __builtin_amdgcn_mfma_f32_16x16x32_bf16(k0.v, qf.v, zc, 0, 0, 0);
        f32x4 d1 = __builtin_amdgcn_mfma_f32_16x16x32_bf16(k1.v, qf.v, zc, 0, 0, 0);
#pragma unroll
        for (int r = 0; r < 4; ++r) { d0[r] = exp2f(d0[r]); d1[r] = exp2f(d1[r]); }
        union { bf16x8 v; unsigned u[4]; } pa;
        pa.u[0] = packbf(d0[0], d0[1]);
        pa.u[1] = packbf(d0[2], d0[3]);
        pa.u[2] = packbf(d1[0], d1[1]);
        pa.u[3] = packbf(d1[2], d1[3]);
        acc = __builtin_amdgcn_mfma_f32_16x16x32_bf16(pa.v, vf.v, acc, 0, 0, 0);
    }

    // remainder (iteration index NU): diagonal region, owned by wave NU&3
    if ((NU & 3) == w) {
        const int j0 = NU * 32;
        union { bf16x8 v; uint4 u; } k0, k1, vf;
        union { bf16x8 v; unsigned u[4]; } pa;
        vf.u = Vp[(NU << 6) + l];
        if (i0 & 16) {
            k0.u = Ktp[j0 + li];
            k1.u = Ktp[j0 + 16 + li];
            f32x4 d0 = __builtin_amdgcn_mfma_f32_16x16x32_bf16(k0.v, qf.v, zc, 0, 0, 0);
            f32x4 d1 = __builtin_amdgcn_mfma_f32_16x16x32_bf16(k1.v, qf.v, zc, 0, 0, 0);
#pragma unroll
            for (int r = 0; r < 4; ++r) {
                d0[r] = exp2f(d0[r]);
                d1[r] = (r <= mconst) ? exp2f(d1[r]) : 0.f;
            }
            pa.u[0] = packbf(d0[0], d0[1]);
            pa.u[1] = packbf(d0[2], d0[3]);
            pa.u[2] = packbf(d1[0], d1[1]);
            pa.u[3] = packbf(d1[2], d1[3]);
        } else {
            k0.u = Ktp[j0 + li];
            f32x4 d0 = __builtin_amdgcn_mfma_f32_16x16x32_bf16(k0.v, qf.v, zc, 0, 0, 0);
#pragma unroll
            for (int r = 0; r < 4; ++r)
                d0[r] = (r <= mconst) ? exp2f(d0[r]) : 0.f;
            pa.u[0] = packbf(d0[0], d0[1]);
            pa.u[1] = packbf(d0[2], d0[3]);
            pa.u[2] = 0u;
            pa.u[3] = 0u;
        }
        acc = __builtin_amdgcn_mfma_f32_16x16x32_bf16(pa.v, vf.v, acc, 0, 0, 0);
    }

    // merge 4 waves' additive partials through LDS (b128, 2-way conflict = free)
    __shared__ f32x4 lds[4][64];
    lds[w][l] = acc;
    __syncthreads();
    if (w != 0) return;
#pragma unroll
    for (int ww = 1; ww < 4; ++ww) {
        const f32x4 o = lds[ww][l];
#pragma unroll
        for (int r = 0; r < 4; ++r) acc[r] += o[r];
    }

    // acc = D[row=4g+r][col=li]; col 8 = rowsum (ones row of V).
    const int idxR = ((g << 4) + 8) << 2;
    float inv[4];
#pragma unroll
    for (int r = 0; r < 4; ++r) {
        const float rs = __int_as_float(
            __builtin_amdgcn_ds_bpermute(idxR, __float_as_int(acc[r])));
        inv[r] = 1.0f / rs;
    }
    if (li < CK) {
#pragma unroll
        for (int r = 0; r < 4; ++r)
            OUT[(prob * CK + li) * SEQ + i0 + 4 * g + r] = acc[r] * inv[r];
    }
}

extern "C" void kernel_launch(void* const* d_in, const int* in_sizes, int n_in,
                              void* d_out, int out_size, void* d_ws, size_t ws_size,
                              hipStream_t stream) {
    // setup_inputs order: keys, queries, values, attn_mask (=tril, folded), num_heads (=8)
    const float* K = (const float*)d_in[0];
    const float* Q = (const float*)d_in[1];
    const float* V = (const float*)d_in[2];
    float* OUT = (float*)d_out;

    // ws layout (bytes): Qt[0, 786432) Kt[786432, 1572864) V16[1572864, 3145728)
    uint4* Qt4  = (uint4*)d_ws;
    uint4* Kt4  = (uint4*)((char*)d_ws + 786432);
    uint4* V164 = (uint4*)((char*)d_ws + 1572864);

    prepass<<<dim3((T1 + T2 + T3) / 256), dim3(256), 0, stream>>>(K, Q, V, Qt4, Kt4, V164);
    // MEASUREMENT: 5 identical (idempotent) launches -> dur8 - dur7 ~= 4*A.
    for (int rep = 0; rep < 5; ++rep)
        attn_main<<<dim3(NPROB * NSTRIP), dim3(256), 0, stream>>>(Qt4, Kt4, V164, OUT);
}

// Round 10
// 91.223 us; speedup vs baseline: 1.7713x; 1.7713x over previous
//
#include <hip/hip_runtime.h>
#include <hip/hip_bf16.h>

// CausalAttentionPixelBlock: 24 independent causal attns (3 stacks x 8 heads),
// seq=2048, head dim ck=8, fp32 in/out, channels-first [c][pos].
// R9 measurement: floor ~59us (harness fills/restores), prepass ~16us (!),
// attn_main ~17us. R10: re-parallelized prepass (4x threads, <=4 loads each);
// attn_main unchanged except unroll 4.
constexpr int NPROB  = 24;
constexpr int SEQ    = 2048;
constexpr int CK     = 8;
constexpr int NSTRIP = SEQ / 16;   // 128 strips of 16 query rows per prob

typedef __attribute__((ext_vector_type(8))) short bf16x8;  // MFMA A/B frag (8 bf16)
typedef __attribute__((ext_vector_type(4))) float f32x4;   // MFMA C/D frag

// ck^-0.5 * log2(e): exp(x) -> exp2(x') with scale folded into Q
__device__ constexpr float QSCALE = 0.35355339059327373f * 1.4426950408889634f;

__device__ inline unsigned packbf(float a, float b) {
    float2 t{a, b};
    __hip_bfloat162 h = __float22bfloat162_rn(t);
    unsigned r; __builtin_memcpy(&r, &h, 4); return r;
}

// ---------------- prepass: fp32 -> bf16 fragments in ws ----------------
// Qt: [prob][j][8] bf16 (Q transposed, pre-scaled)                     786 KB
// Kt: [prob][j][8] bf16 (K transposed)                                 786 KB
// V16:[prob][chunk][64] uint4, chunk = 32 keys. Entry (chunk p, l=g*16+row):
//     V[row][32p + {4g..4g+3, 16+4g..16+4g+3}] (sigma key order). Row 8 = 1.0
//     (free rowsum), rows 9-15 = 0.                                    1.57 MB
// Section A: thread per (prob, j, cpair): 4 loads, 2 uint stores; the uint
// store index IS the thread index (exact Qt/Kt linear layout), coalesced.
constexpr int TA = NPROB * SEQ * 4;        // Qt+Kt: (prob, j, cpair)   196608
constexpr int TB = NPROB * CK * (SEQ / 8); // V16 rows 0-7               49152
constexpr int TC = NPROB * 8  * (SEQ / 8); // V16 rows 8-15 fill         49152

__global__ __launch_bounds__(256) void prepass(
    const float* __restrict__ K, const float* __restrict__ Q,
    const float* __restrict__ V,
    uint4* __restrict__ Qt4, uint4* __restrict__ Kt4, uint4* __restrict__ V164)
{
    const int t = blockIdx.x * 256 + threadIdx.x;
    if (t < TA) {
        const int cp   = t & 3;            // channel pair 0..3
        const int j    = (t >> 2) & (SEQ - 1);
        const int prob = t >> 13;
        const float* qs = Q + prob * CK * SEQ + (cp << 1) * SEQ + j;
        const float* ks = K + prob * CK * SEQ + (cp << 1) * SEQ + j;
        ((unsigned*)Qt4)[t] = packbf(qs[0] * QSCALE, qs[SEQ] * QSCALE);
        ((unsigned*)Kt4)[t] = packbf(ks[0], ks[SEQ]);
    } else if (t < TA + TB) {
        const int idx  = t - TA;
        const int prob = idx >> 11;
        const int rem  = idx & 2047;
        const int c    = rem >> 8;             // V row (channel) 0..7
        const int u    = rem & 255;
        const int c32  = u >> 2;               // 32-key chunk 0..63
        const int g    = u & 3;                // k-group within chunk
        const float* vs = V + prob * CK * SEQ + c * SEQ + c32 * 32;
        const float4 a = *reinterpret_cast<const float4*>(vs + 4 * g);       // keys 4g..4g+3
        const float4 b = *reinterpret_cast<const float4*>(vs + 16 + 4 * g);  // keys 16+4g..
        uint4 vo;
        vo.x = packbf(a.x, a.y); vo.y = packbf(a.z, a.w);
        vo.z = packbf(b.x, b.y); vo.w = packbf(b.z, b.w);
        V164[prob * 4096 + c32 * 64 + g * 16 + c] = vo;   // [prob][chunk][g*16+row]
    } else {
        const int idx  = t - TA - TB;
        const int prob = idx >> 11;
        const int rem  = idx & 2047;
        const int r    = rem >> 8;             // 0..7 -> row 8+r
        const int u    = rem & 255;
        const int c32  = u >> 2;
        const int g    = u & 3;
        const unsigned w = (r == 0) ? 0x3F803F80u : 0u;  // row 8 = ones (rowsum)
        V164[prob * 4096 + c32 * 64 + g * 16 + (8 + r)] = uint4{w, w, w, w};
    }
}

// ---------------- main: one 4-wave block per 16-row strip ----------------
// QK transposed: d = mfma16x16x32(A=K, B=Q) -> lane(g,li) reg r = P[j'=4g+r(+16)][i'=li].
// exp2 in place, pack to bf16: pa = {d0r01, d0r23, d1r01, d1r23} is EXACTLY the
// PV A-frag under key-order sigma(8g+e) = 4g+e | 16+4g+(e-4); V staged in sigma
// order, so PV = mfma(A=pa, B=V) with no cross-lane ops. V row 8 = ones gives
// the softmax denominator in acc col 8.
// Note: bid%24 = prob and 24%8==0 -> all blocks of a prob land on one XCD
// (round-robin assumption), keeping its ~130KB working set L2-local.
__global__ __launch_bounds__(256) void attn_main(
    const uint4* __restrict__ Qt4, const uint4* __restrict__ Kt4,
    const uint4* __restrict__ V164, float* __restrict__ OUT)
{
    const int bid   = blockIdx.x;
    const int prob  = bid % NPROB;
    const int strip = (NSTRIP - 1) - (bid / NPROB);  // longest first
    const int i0    = strip * 16;
    const int t  = threadIdx.x;
    const int w  = t >> 6;                  // wave 0..3
    const int l  = t & 63;                  // lane
    const int li = l & 15, g = l >> 4;

    const uint4* Ktp = Kt4 + prob * SEQ;
    const uint4* Vp  = V164 + prob * 4096;  // [64 chunks][64] uint4

    union { bf16x8 v; uint4 u; } qf;
    qf.u = (g == 0) ? Qt4[prob * SEQ + i0 + li] : uint4{0, 0, 0, 0};

    f32x4 acc = {0.f, 0.f, 0.f, 0.f};
    const f32x4 zc = {0.f, 0.f, 0.f, 0.f};
    const int mconst = li - 4 * g;          // diag tile: keep reg r iff r <= mconst

    const int NU = i0 >> 5;                 // fully-unmasked 32-j iterations

#pragma unroll 4
    for (int p = w; p < NU; p += 4) {
        const int j0 = p * 32;
        union { bf16x8 v; uint4 u; } k0, k1, vf;
        k0.u = Ktp[j0 + li];                // keys j0..j0+15 (broadcast x4)
        k1.u = Ktp[j0 + 16 + li];           // keys j0+16..j0+31
        vf.u = Vp[(p << 6) + l];            // sigma-interleaved V, coalesced
        f32x4 d0 = __builtin_amdgcn_mfma_f32_16x16x32_bf16(k0.v, qf.v, zc, 0, 0, 0);
        f32x4 d1 = __builtin_amdgcn_mfma_f32_16x16x32_bf16(k1.v, qf.v, zc, 0, 0, 0);
#pragma unroll
        for (int r = 0; r < 4; ++r) { d0[r] = exp2f(d0[r]); d1[r] = exp2f(d1[r]); }
        union { bf16x8 v; unsigned u[4]; } pa;
        pa.u[0] = packbf(d0[0], d0[1]);
        pa.u[1] = packbf(d0[2], d0[3]);
        pa.u[2] = packbf(d1[0], d1[1]);
        pa.u[3] = packbf(d1[2], d1[3]);
        acc = __builtin_amdgcn_mfma_f32_16x16x32_bf16(pa.v, vf.v, acc, 0, 0, 0);
    }

    // remainder (iteration index NU): diagonal region, owned by wave NU&3
    if ((NU & 3) == w) {
        const int j0 = NU * 32;
        union { bf16x8 v; uint4 u; } k0, k1, vf;
        union { bf16x8 v; unsigned u[4]; } pa;
        vf.u = Vp[(NU << 6) + l];
        if (i0 & 16) {
            k0.u = Ktp[j0 + li];
            k1.u = Ktp[j0 + 16 + li];
            f32x4 d0 = __builtin_amdgcn_mfma_f32_16x16x32_bf16(k0.v, qf.v, zc, 0, 0, 0);
            f32x4 d1 = __builtin_amdgcn_mfma_f32_16x16x32_bf16(k1.v, qf.v, zc, 0, 0, 0);
#pragma unroll
            for (int r = 0; r < 4; ++r) {
                d0[r] = exp2f(d0[r]);
                d1[r] = (r <= mconst) ? exp2f(d1[r]) : 0.f;
            }
            pa.u[0] = packbf(d0[0], d0[1]);
            pa.u[1] = packbf(d0[2], d0[3]);
            pa.u[2] = packbf(d1[0], d1[1]);
            pa.u[3] = packbf(d1[2], d1[3]);
        } else {
            k0.u = Ktp[j0 + li];
            f32x4 d0 = __builtin_amdgcn_mfma_f32_16x16x32_bf16(k0.v, qf.v, zc, 0, 0, 0);
#pragma unroll
            for (int r = 0; r < 4; ++r)
                d0[r] = (r <= mconst) ? exp2f(d0[r]) : 0.f;
            pa.u[0] = packbf(d0[0], d0[1]);
            pa.u[1] = packbf(d0[2], d0[3]);
            pa.u[2] = 0u;
            pa.u[3] = 0u;
        }
        acc = __builtin_amdgcn_mfma_f32_16x16x32_bf16(pa.v, vf.v, acc, 0, 0, 0);
    }

    // merge 4 waves' additive partials through LDS (b128, 2-way conflict = free)
    __shared__ f32x4 lds[4][64];
    lds[w][l] = acc;
    __syncthreads();
    if (w != 0) return;
#pragma unroll
    for (int ww = 1; ww < 4; ++ww) {
        const f32x4 o = lds[ww][l];
#pragma unroll
        for (int r = 0; r < 4; ++r) acc[r] += o[r];
    }

    // acc = D[row=4g+r][col=li]; col 8 = rowsum (ones row of V).
    const int idxR = ((g << 4) + 8) << 2;
    float inv[4];
#pragma unroll
    for (int r = 0; r < 4; ++r) {
        const float rs = __int_as_float(
            __builtin_amdgcn_ds_bpermute(idxR, __float_as_int(acc[r])));
        inv[r] = 1.0f / rs;
    }
    if (li < CK) {
#pragma unroll
        for (int r = 0; r < 4; ++r)
            OUT[(prob * CK + li) * SEQ + i0 + 4 * g + r] = acc[r] * inv[r];
    }
}

extern "C" void kernel_launch(void* const* d_in, const int* in_sizes, int n_in,
                              void* d_out, int out_size, void* d_ws, size_t ws_size,
                              hipStream_t stream) {
    // setup_inputs order: keys, queries, values, attn_mask (=tril, folded), num_heads (=8)
    const float* K = (const float*)d_in[0];
    const float* Q = (const float*)d_in[1];
    const float* V = (const float*)d_in[2];
    float* OUT = (float*)d_out;

    // ws layout (bytes): Qt[0, 786432) Kt[786432, 1572864) V16[1572864, 3145728)
    uint4* Qt4  = (uint4*)d_ws;
    uint4* Kt4  = (uint4*)((char*)d_ws + 786432);
    uint4* V164 = (uint4*)((char*)d_ws + 1572864);

    prepass<<<dim3((TA + TB + TC) / 256), dim3(256), 0, stream>>>(K, Q, V, Qt4, Kt4, V164);
    attn_main<<<dim3(NPROB * NSTRIP), dim3(256), 0, stream>>>(Qt4, Kt4, V164, OUT);
}